// Round 12
// baseline (120.707 us; speedup 1.0000x reference)
//
#include <hip/hip_runtime.h>
#include <hip/hip_bf16.h>

// AutoCorrelation (Autoformer): FFT-based circular cross-correlation,
// top-8 delays, softmax weights, rolled-value aggregation.
// B=8, L=4096, H=8, D=32, K=8. Layout [B,L,H,D]: idx = b*1048576 + l*256 + h*32 + d.
//
// R11: transpose reverted to plain float4 loads (R10's NT loads regressed);
//      fwd_spd software-pipelined: col1's global loads issued into registers
//      before col0's FFT (T14 async-stage), written to LDS after col0's
//      product. SLICE=2048 + separate nyq kept from R10.

#define SWZ(i) ((i) ^ (((i) >> 4) & 15))   // float2-index swizzle: pos ^= row&15
#define SLICE 2048                          // float2 per spd_d slice (16 KB aligned)

typedef float nfloat4 __attribute__((ext_vector_type(4)));   // native vec for builtins

__device__ inline void cmul(float& outr, float& outi, float ar, float ai, float br, float bi) {
    outr = ar * br - ai * bi;
    outi = ar * bi + ai * br;
}

// 16-point DFT in registers. DIR=-1 forward, +1 inverse (no 1/N scale).
template<int DIR>
__device__ inline void fft16(float* vr, float* vi) {
    const float C1 = 0.92387953251128675613f;  // cos(pi/8)
    const float S1 = 0.38268343236508977173f;  // sin(pi/8)
    const float R2 = 0.70710678118654752440f;  // sqrt(2)/2
    float ur[16], ui[16];
#pragma unroll
    for (int n2 = 0; n2 < 4; ++n2) {
        float ar = vr[n2],      ai = vi[n2];
        float br = vr[n2 + 4],  bi = vi[n2 + 4];
        float cr = vr[n2 + 8],  ci = vi[n2 + 8];
        float dr = vr[n2 + 12], di = vi[n2 + 12];
        float acr = ar + cr, aci = ai + ci;
        float asr = ar - cr, asi = ai - ci;
        float bdr = br + dr, bdi = bi + di;
        float bsr = br - dr, bsi = bi - di;
        ur[0 + n2]  = acr + bdr; ui[0 + n2]  = aci + bdi;
        ur[8 + n2]  = acr - bdr; ui[8 + n2]  = aci - bdi;
        if (DIR < 0) {
            ur[4 + n2]  = asr + bsi; ui[4 + n2]  = asi - bsr;
            ur[12 + n2] = asr - bsi; ui[12 + n2] = asi + bsr;
        } else {
            ur[4 + n2]  = asr - bsi; ui[4 + n2]  = asi + bsr;
            ur[12 + n2] = asr + bsi; ui[12 + n2] = asi - bsr;
        }
    }
#pragma unroll
    for (int k1 = 1; k1 < 4; ++k1) {
#pragma unroll
        for (int n2 = 1; n2 < 4; ++n2) {
            int e = k1 * n2;        // in {1,2,3,4,6,9}
            float c, s;
            if (e == 1)      { c = C1;  s = S1; }
            else if (e == 2) { c = R2;  s = R2; }
            else if (e == 3) { c = S1;  s = C1; }
            else if (e == 4) { c = 0.f; s = 1.f; }
            else if (e == 6) { c = -R2; s = R2; }
            else             { c = -C1; s = -S1; }   // e == 9
            int idx = k1 * 4 + n2;
            float r0 = ur[idx], i0 = ui[idx];
            if (DIR < 0) { ur[idx] = r0 * c + i0 * s; ui[idx] = i0 * c - r0 * s; }
            else         { ur[idx] = r0 * c - i0 * s; ui[idx] = i0 * c + r0 * s; }
        }
    }
#pragma unroll
    for (int k1 = 0; k1 < 4; ++k1) {
        float ar = ur[k1 * 4 + 0], ai = ui[k1 * 4 + 0];
        float br = ur[k1 * 4 + 1], bi = ui[k1 * 4 + 1];
        float cr = ur[k1 * 4 + 2], ci = ui[k1 * 4 + 2];
        float dr = ur[k1 * 4 + 3], di = ui[k1 * 4 + 3];
        float acr = ar + cr, aci = ai + ci;
        float asr = ar - cr, asi = ai - ci;
        float bdr = br + dr, bdi = bi + di;
        float bsr = br - dr, bsi = bi - di;
        vr[k1]      = acr + bdr; vi[k1]      = aci + bdi;
        vr[k1 + 8]  = acr - bdr; vi[k1 + 8]  = aci - bdi;
        if (DIR < 0) {
            vr[k1 + 4]  = asr + bsi; vi[k1 + 4]  = asi - bsr;
            vr[k1 + 12] = asr - bsi; vi[k1 + 12] = asi + bsr;
        } else {
            vr[k1 + 4]  = asr - bsi; vi[k1 + 4]  = asi + bsr;
            vr[k1 + 12] = asr + bsi; vi[k1 + 12] = asi - bsr;
        }
    }
}

// In-place radix-16 Stockham pass; w1 = per-thread base twiddle (already
// direction-adjusted by the caller).
template<int DIR, int NS>
__device__ inline void fft_pass16_ip(float2* __restrict__ buf,
                                     float w1r, float w1i, int j) {
    float vr[16], vi[16];
#pragma unroll
    for (int r = 0; r < 16; ++r) {
        float2 x = buf[SWZ(j + r * 256)];
        vr[r] = x.x; vi[r] = x.y;
    }
    if (NS > 1) {
        float wr[16], wi[16];
        wr[1] = w1r; wi[1] = w1i;
#pragma unroll
        for (int r = 2; r < 16; ++r)        // log-depth ladder: w^r = w^(r/2) * w^((r+1)/2)
            cmul(wr[r], wi[r], wr[r >> 1], wi[r >> 1], wr[(r + 1) >> 1], wi[(r + 1) >> 1]);
#pragma unroll
        for (int r = 1; r < 16; ++r) {
            float r0 = vr[r], i0 = vi[r];
            vr[r] = r0 * wr[r] - i0 * wi[r];
            vi[r] = r0 * wi[r] + i0 * wr[r];
        }
    }
    fft16<DIR>(vr, vi);
    __syncthreads();                        // all reads done before any write
    int base = (j / NS) * (16 * NS) + (j & (NS - 1));
#pragma unroll
    for (int r = 0; r < 16; ++r)
        buf[SWZ(base + r * NS)] = make_float2(vr[r], vi[r]);
}

// 3 in-place passes; result in buf, natural order (swizzled).
// (c2,s2): twiddle for pass2 (m=(tid&15)*16); (c3,s3): pass3 (m=tid).
// s already negated for forward by caller.
template<int DIR>
__device__ inline void fft4096_ip(float2* buf, float c2, float s2,
                                  float c3, float s3, int tid) {
    fft_pass16_ip<DIR, 1>(buf, 1.f, 0.f, tid);  __syncthreads();
    fft_pass16_ip<DIR, 16>(buf, c2, s2, tid);   __syncthreads();
    fft_pass16_ip<DIR, 256>(buf, c3, s3, tid);  __syncthreads();
}

// Transpose+pack: q,k [B, L, 256] -> xT[b, c, l] = float2(q, k), c = h*32+d.
__global__ __launch_bounds__(256) void transpose_pack_kernel(const float4* __restrict__ q4,
                                                             const float4* __restrict__ k4,
                                                             float4* __restrict__ xT4) {
    __shared__ float qs[64][65];
    __shared__ float ks[64][65];
    int bid = blockIdx.x;             // b*256 + lt*4 + ct
    int ct = bid & 3;
    int lt = (bid >> 2) & 63;
    int b  = bid >> 8;
    int tid = threadIdx.x;
    int l0 = lt * 64, c0 = ct * 64;
    int cw = tid & 15;
    int rr = tid >> 4;
#pragma unroll
    for (int it = 0; it < 4; ++it) {
        int row = it * 16 + rr;       // l_local
        size_t g = (size_t)(b * 4096 + l0 + row) * 64u + (size_t)(c0 / 4 + cw);
        float4 qv = q4[g];
        float4 kv = k4[g];
        qs[row][cw * 4 + 0] = qv.x; qs[row][cw * 4 + 1] = qv.y;
        qs[row][cw * 4 + 2] = qv.z; qs[row][cw * 4 + 3] = qv.w;
        ks[row][cw * 4 + 0] = kv.x; ks[row][cw * 4 + 1] = kv.y;
        ks[row][cw * 4 + 2] = kv.z; ks[row][cw * 4 + 3] = kv.w;
    }
    __syncthreads();
    int a = tid & 31;                 // l-pair index (2 l per thread)
    int cb = tid >> 5;
#pragma unroll
    for (int it = 0; it < 8; ++it) {
        int cc = it * 8 + cb;         // c_local
        float4 o;
        o.x = qs[2 * a][cc];     o.y = ks[2 * a][cc];
        o.z = qs[2 * a + 1][cc]; o.w = ks[2 * a + 1][cc];
        xT4[(size_t)(b * 256 + c0 + cc) * 2048u + (size_t)(l0 / 2 + a)] = o;
    }
}

// Spectral product for an f-pair layout: thread t handles f0 = 2*tid+512*t.
__device__ inline void spd_pair_accum(const float2* A, float4* acc, float& accny, int tid) {
#pragma unroll
    for (int t = 0; t < 4; ++t) {
        int f0 = 2 * tid + 512 * t;
        float2 za = A[SWZ(f0)];
        float2 zb = A[SWZ(f0 + 1)];
        float2 ma = A[SWZ((4096 - f0) & 4095)];
        float2 mb = A[SWZ(4095 - f0)];
        // elem 0: z1=za, z2=ma
        float qr = za.x + ma.x, qi = za.y - ma.y;
        float kr = za.y + ma.y, ki = za.x - ma.x;
        acc[t].x += 0.25f * (qr * kr - qi * ki);
        acc[t].y += 0.25f * (qr * ki + qi * kr);
        // elem 1: z1=zb, z2=mb
        qr = zb.x + mb.x; qi = zb.y - mb.y;
        kr = zb.y + mb.y; ki = zb.x - mb.x;
        acc[t].z += 0.25f * (qr * kr - qi * ki);
        acc[t].w += 0.25f * (qr * ki + qi * kr);
    }
    float2 zn = A[SWZ(2048)];          // broadcast read
    accny += zn.x * zn.y;              // Q_nyq * K_nyq (both real)
}

// K1 fast: one block per (b, column-pair p). Col1's global loads issued into
// registers BEFORE col0's FFT (latency hidden under compute); written to LDS
// after col0's product. 32 KB LDS, 4 blocks/CU.
__global__ __launch_bounds__(256, 4) void fwd_spd_fast(const float2* __restrict__ xT,
                                                       float2* __restrict__ spd_d,
                                                       float* __restrict__ nyq) {
    __shared__ float2 A[4096];             // 32 KB
    int bid = blockIdx.x;                  // b*128 + p
    int tid = threadIdx.x;
    int b = bid >> 7, p = bid & 127;
    const float TWO_PI = 6.2831853071795864769f;
    float ang2 = TWO_PI * (float)((tid & 15) * 16) * (1.0f / 4096.0f);
    float ang3 = TWO_PI * (float)tid * (1.0f / 4096.0f);
    float c2 = cosf(ang2), s2 = sinf(ang2);
    float c3 = cosf(ang3), s3 = sinf(ang3);
    float4 acc[4];
#pragma unroll
    for (int t = 0; t < 4; ++t) acc[t] = make_float4(0.f, 0.f, 0.f, 0.f);
    float accny = 0.f;

    const float4* src0 = (const float4*)(xT + (size_t)(b * 256 + p * 2) * 4096u);
    const float4* src1 = src0 + 2048;      // second column, contiguous

    // col0 -> LDS directly
#pragma unroll
    for (int t = 0; t < 8; ++t) {
        float4 x = src0[tid + t * 256];
        int n = 2 * (tid + t * 256);
        A[SWZ(n)]     = make_float2(x.x, x.y);
        A[SWZ(n + 1)] = make_float2(x.z, x.w);
    }
    // col1 -> registers (in flight across col0's FFT)
    float4 x1[8];
#pragma unroll
    for (int t = 0; t < 8; ++t) x1[t] = src1[tid + t * 256];

    __syncthreads();
    fft4096_ip<-1>(A, c2, -s2, c3, -s3, tid);
    spd_pair_accum(A, acc, accny, tid);
    __syncthreads();                       // product reads done before overwrite

    // col1 registers -> LDS (loads long since landed)
#pragma unroll
    for (int t = 0; t < 8; ++t) {
        int n = 2 * (tid + t * 256);
        A[SWZ(n)]     = make_float2(x1[t].x, x1[t].y);
        A[SWZ(n + 1)] = make_float2(x1[t].z, x1[t].w);
    }
    __syncthreads();
    fft4096_ip<-1>(A, c2, -s2, c3, -s3, tid);
    spd_pair_accum(A, acc, accny, tid);

    float4* dst4 = (float4*)(spd_d + (size_t)bid * SLICE);
#pragma unroll
    for (int t = 0; t < 4; ++t) dst4[tid + t * 256] = acc[t];
    if (tid == 0) nyq[bid] = accny;
}

// K1 slow fallback: strided loads straight from q,k; full 3-pass FFT.
__global__ __launch_bounds__(256, 4) void fwd_spd_slow(const float* __restrict__ q,
                                                       const float* __restrict__ k,
                                                       float2* __restrict__ spd_d,
                                                       float* __restrict__ nyq) {
    __shared__ float2 A[4096];
    int bid = blockIdx.x;                 // b*128 + p
    int tid = threadIdx.x;
    int b = bid >> 7, p = bid & 127;
    const float TWO_PI = 6.2831853071795864769f;
    float ang2 = TWO_PI * (float)((tid & 15) * 16) * (1.0f / 4096.0f);
    float ang3 = TWO_PI * (float)tid * (1.0f / 4096.0f);
    float c2 = cosf(ang2), s2 = sinf(ang2);
    float c3 = cosf(ang3), s3 = sinf(ang3);
    float4 acc[4];
#pragma unroll
    for (int t = 0; t < 4; ++t) acc[t] = make_float4(0.f, 0.f, 0.f, 0.f);
    float accny = 0.f;
#pragma unroll
    for (int cc = 0; cc < 2; ++cc) {
        if (cc) __syncthreads();
        size_t base = (size_t)b * 1048576u + (size_t)(p * 2 + cc);
#pragma unroll
        for (int t = 0; t < 16; ++t) {
            int n = tid + t * 256;
            A[SWZ(n)] = make_float2(q[base + (size_t)n * 256u], k[base + (size_t)n * 256u]);
        }
        __syncthreads();
        fft4096_ip<-1>(A, c2, -s2, c3, -s3, tid);
        spd_pair_accum(A, acc, accny, tid);
    }
    float4* dst4 = (float4*)(spd_d + (size_t)bid * SLICE);
#pragma unroll
    for (int t = 0; t < 4; ++t) dst4[tid + t * 256] = acc[t];
    if (tid == 0) nyq[bid] = accny;
}

// K2: one block per (b,h). Fused d-reduce (16 slices, float4), mirror Hermitian
// spectrum, inverse FFT (x 1/N), register top-8 (ties -> lowest idx), softmax.
__global__ __launch_bounds__(256, 4) void ifft_topk_kernel(const float2* __restrict__ spd_d,
                                                           const float* __restrict__ nyq,
                                                           float* __restrict__ wout,
                                                           int* __restrict__ dout) {
    __shared__ float2 A[4096];
    __shared__ float rv[8][4];
    __shared__ int   ri[8][4];
    int bh = blockIdx.x;
    int b = bh >> 3, h = bh & 7;
    int tid = threadIdx.x;
    const float TWO_PI = 6.2831853071795864769f;
    float ang2 = TWO_PI * (float)((tid & 15) * 16) * (1.0f / 4096.0f);
    float ang3 = TWO_PI * (float)tid * (1.0f / 4096.0f);
    float c2 = cosf(ang2), s2 = sinf(ang2);
    float c3 = cosf(ang3), s3 = sinf(ang3);
    const float sc = 1.0f / 4096.0f;
    const float4* base4 = (const float4*)(spd_d + (size_t)(b * 128 + h * 16) * SLICE);
#pragma unroll
    for (int t = 0; t < 4; ++t) {
        int f0 = 2 * tid + 512 * t;
        float4 a = make_float4(0.f, 0.f, 0.f, 0.f);
#pragma unroll
        for (int s = 0; s < 16; ++s) {
            float4 x = base4[(size_t)s * (SLICE / 2) + (size_t)(tid + 256 * t)];
            a.x += x.x; a.y += x.y; a.z += x.z; a.w += x.w;
        }
        float r0 = a.x * sc, i0 = a.y * sc;
        float r1 = a.z * sc, i1 = a.w * sc;
        A[SWZ(f0)]     = make_float2(r0, i0);
        A[SWZ(f0 + 1)] = make_float2(r1, i1);
        if (f0 > 0) A[SWZ(4096 - f0)] = make_float2(r0, -i0);
        A[SWZ(4095 - f0)] = make_float2(r1, -i1);
    }
    if (tid == 0) {
        float ny = 0.f;
#pragma unroll
        for (int s = 0; s < 16; ++s) ny += nyq[b * 128 + h * 16 + s];
        A[SWZ(2048)] = make_float2(ny * sc, 0.f);
    }
    __syncthreads();
    fft4096_ip<1>(A, c2, s2, c3, s3, tid);
    // corr[tau] = A[SWZ(tau)].x -> registers
    float cv[16];
#pragma unroll
    for (int t = 0; t < 16; ++t) cv[t] = A[SWZ(tid + t * 256)].x;

    int lane = tid & 63, wid = tid >> 6;
    float topv[8]; int topi[8];
    for (int kk = 0; kk < 8; ++kk) {
        float best = -3.0e38f; int bi = 0;
#pragma unroll
        for (int t = 0; t < 16; ++t) {
            int f = tid + t * 256;
            if (cv[t] > best) { best = cv[t]; bi = f; }   // strict > keeps lowest f
        }
#pragma unroll
        for (int off = 32; off > 0; off >>= 1) {
            float ov = __shfl_xor(best, off, 64);
            int   oi = __shfl_xor(bi, off, 64);
            if (ov > best || (ov == best && oi < bi)) { best = ov; bi = oi; }
        }
        if (lane == 0) { rv[kk][wid] = best; ri[kk][wid] = bi; }
        __syncthreads();
        float fb = rv[kk][0]; int fi = ri[kk][0];
#pragma unroll
        for (int w = 1; w < 4; ++w) {
            float ov = rv[kk][w]; int oi = ri[kk][w];
            if (ov > fb || (ov == fb && oi < fi)) { fb = ov; fi = oi; }
        }
        topv[kk] = fb; topi[kk] = fi;
        if (tid == (fi & 255)) {              // owner clears winner (static reg idx)
            int t_owner = fi >> 8;
#pragma unroll
            for (int t = 0; t < 16; ++t)
                if (t == t_owner) cv[t] = -3.0e38f;
        }
    }
    if (tid == 0) {
        float mx = topv[0];
        float e[8], s = 0.0f;
#pragma unroll
        for (int kk = 0; kk < 8; ++kk) { e[kk] = expf(topv[kk] - mx); s += e[kk]; }
        float inv = 1.0f / s;
#pragma unroll
        for (int kk = 0; kk < 8; ++kk) {
            wout[bh * 8 + kk] = e[kk] * inv;
            dout[bh * 8 + kk] = topi[kk];
        }
    }
}

// K3: b-major grid (b = blk & 7 -> per-XCD L2 residency of v[b], 4 MiB).
// One block per 16 l's; thread = (lq, c4), 4 reps; nontemporal out stores.
__global__ __launch_bounds__(256) void agg_kernel(const float4* __restrict__ v4,
                                                  const float* __restrict__ w,
                                                  const int* __restrict__ dl,
                                                  float4* __restrict__ out4) {
    __shared__ float sw[64];
    __shared__ int   sd[64];
    int blk = blockIdx.x;              // lg*8 + b  (b fastest -> XCD round-robin)
    int b = blk & 7, lg = blk >> 3;    // lg in [0,256), 16 l's each
    int tid = threadIdx.x;
    if (tid < 64) {
        int h = tid >> 3, kk = tid & 7;
        sw[tid] = w[(b * 8 + h) * 8 + kk];
        sd[tid] = dl[(b * 8 + h) * 8 + kk];
    }
    __syncthreads();
    int lq = tid >> 6;                 // 0..3
    int c4 = tid & 63;                 // float4 index over 256 floats
    int h  = c4 >> 3;
    float w_[8]; int d_[8];
#pragma unroll
    for (int kk = 0; kk < 8; ++kk) { w_[kk] = sw[h * 8 + kk]; d_[kk] = sd[h * 8 + kk]; }
#pragma unroll
    for (int rep = 0; rep < 4; ++rep) {
        int l = lg * 16 + rep * 4 + lq;
        float4 acc = make_float4(0.f, 0.f, 0.f, 0.f);
#pragma unroll
        for (int kk = 0; kk < 8; ++kk) {
            int l2 = (l + d_[kk]) & 4095;
            float4 x = v4[(size_t)(b * 4096 + l2) * 64u + (size_t)c4];
            acc.x += w_[kk] * x.x; acc.y += w_[kk] * x.y;
            acc.z += w_[kk] * x.z; acc.w += w_[kk] * x.w;
        }
        nfloat4 nv = {acc.x, acc.y, acc.z, acc.w};
        __builtin_nontemporal_store(nv,
            (nfloat4*)&out4[(size_t)(b * 4096 + l) * 64u + (size_t)c4]);
    }
}

extern "C" void kernel_launch(void* const* d_in, const int* in_sizes, int n_in,
                              void* d_out, int out_size, void* d_ws, size_t ws_size,
                              hipStream_t stream) {
    const float* q = (const float*)d_in[0];
    const float* k = (const float*)d_in[1];
    const float* v = (const float*)d_in[2];
    float* ws  = (float*)d_ws;
    // d_out doubles as spd_d scratch: 1024 slices x SLICE float2 = 16.8 MB
    // (out is 33.5 MB; agg fully rewrites it last).
    float2* spd_d = (float2*)d_out;

    const size_t XT_FLOATS = 16777216u;     // xT: 2048 slices x 4096 complex
    const size_t FAST_FLOATS = XT_FLOATS + 512u + 512u + 1024u;
    bool fast = ws_size >= FAST_FLOATS * sizeof(float);

    if (fast) {
        float* wbuf = ws + XT_FLOATS;       // 512 floats
        int*   dbuf = (int*)(wbuf + 512);   // 512 ints
        float* nyq  = wbuf + 1024;          // 1024 floats
        transpose_pack_kernel<<<2048, 256, 0, stream>>>((const float4*)q, (const float4*)k,
                                                        (float4*)ws);
        fwd_spd_fast<<<1024, 256, 0, stream>>>((const float2*)ws, spd_d, nyq);
        ifft_topk_kernel<<<64, 256, 0, stream>>>(spd_d, nyq, wbuf, dbuf);
        agg_kernel<<<2048, 256, 0, stream>>>((const float4*)v, wbuf, dbuf, (float4*)d_out);
    } else {
        float* wbuf = ws;
        int*   dbuf = (int*)(wbuf + 512);
        float* nyq  = wbuf + 1024;
        fwd_spd_slow<<<1024, 256, 0, stream>>>(q, k, spd_d, nyq);
        ifft_topk_kernel<<<64, 256, 0, stream>>>(spd_d, nyq, wbuf, dbuf);
        agg_kernel<<<2048, 256, 0, stream>>>((const float4*)v, wbuf, dbuf, (float4*)d_out);
    }
}

// Round 13
// 86.989 us; speedup vs baseline: 1.3876x; 1.3876x over previous
//
#include <hip/hip_runtime.h>
#include <hip/hip_bf16.h>

// AutoCorrelation (Autoformer): FFT-based circular cross-correlation,
// top-8 delays, softmax weights, rolled-value aggregation.
// B=8, L=4096, H=8, D=32, K=8. Layout [B,L,H,D]: idx = b*1048576 + l*256 + h*32 + d.
//
// R12: R7-exact pipeline (plain transpose loads, SLICE=2056 w/ Nyquist tail)
//      with ONE change: ping-pong A->B FFT (4 barriers/FFT) instead of
//      in-place (7 barriers/FFT). 64 KB LDS, 2 blocks/CU (LDS-limited).
//      No register prefetch (spilled in R9/R11 — twice confirmed).

#define SWZ(i) ((i) ^ (((i) >> 4) & 15))   // float2-index swizzle: pos ^= row&15
#define SLICE 2056                          // float2 per spd_d slice (breaks 16KB pow2 aliasing)

typedef float nfloat4 __attribute__((ext_vector_type(4)));   // native vec for builtins

__device__ inline void cmul(float& outr, float& outi, float ar, float ai, float br, float bi) {
    outr = ar * br - ai * bi;
    outi = ar * bi + ai * br;
}

// 16-point DFT in registers. DIR=-1 forward, +1 inverse (no 1/N scale).
template<int DIR>
__device__ inline void fft16(float* vr, float* vi) {
    const float C1 = 0.92387953251128675613f;  // cos(pi/8)
    const float S1 = 0.38268343236508977173f;  // sin(pi/8)
    const float R2 = 0.70710678118654752440f;  // sqrt(2)/2
    float ur[16], ui[16];
#pragma unroll
    for (int n2 = 0; n2 < 4; ++n2) {
        float ar = vr[n2],      ai = vi[n2];
        float br = vr[n2 + 4],  bi = vi[n2 + 4];
        float cr = vr[n2 + 8],  ci = vi[n2 + 8];
        float dr = vr[n2 + 12], di = vi[n2 + 12];
        float acr = ar + cr, aci = ai + ci;
        float asr = ar - cr, asi = ai - ci;
        float bdr = br + dr, bdi = bi + di;
        float bsr = br - dr, bsi = bi - di;
        ur[0 + n2]  = acr + bdr; ui[0 + n2]  = aci + bdi;
        ur[8 + n2]  = acr - bdr; ui[8 + n2]  = aci - bdi;
        if (DIR < 0) {
            ur[4 + n2]  = asr + bsi; ui[4 + n2]  = asi - bsr;
            ur[12 + n2] = asr - bsi; ui[12 + n2] = asi + bsr;
        } else {
            ur[4 + n2]  = asr - bsi; ui[4 + n2]  = asi + bsr;
            ur[12 + n2] = asr + bsi; ui[12 + n2] = asi - bsr;
        }
    }
#pragma unroll
    for (int k1 = 1; k1 < 4; ++k1) {
#pragma unroll
        for (int n2 = 1; n2 < 4; ++n2) {
            int e = k1 * n2;        // in {1,2,3,4,6,9}
            float c, s;
            if (e == 1)      { c = C1;  s = S1; }
            else if (e == 2) { c = R2;  s = R2; }
            else if (e == 3) { c = S1;  s = C1; }
            else if (e == 4) { c = 0.f; s = 1.f; }
            else if (e == 6) { c = -R2; s = R2; }
            else             { c = -C1; s = -S1; }   // e == 9
            int idx = k1 * 4 + n2;
            float r0 = ur[idx], i0 = ui[idx];
            if (DIR < 0) { ur[idx] = r0 * c + i0 * s; ui[idx] = i0 * c - r0 * s; }
            else         { ur[idx] = r0 * c - i0 * s; ui[idx] = i0 * c + r0 * s; }
        }
    }
#pragma unroll
    for (int k1 = 0; k1 < 4; ++k1) {
        float ar = ur[k1 * 4 + 0], ai = ui[k1 * 4 + 0];
        float br = ur[k1 * 4 + 1], bi = ui[k1 * 4 + 1];
        float cr = ur[k1 * 4 + 2], ci = ui[k1 * 4 + 2];
        float dr = ur[k1 * 4 + 3], di = ui[k1 * 4 + 3];
        float acr = ar + cr, aci = ai + ci;
        float asr = ar - cr, asi = ai - ci;
        float bdr = br + dr, bdi = bi + di;
        float bsr = br - dr, bsi = bi - di;
        vr[k1]      = acr + bdr; vi[k1]      = aci + bdi;
        vr[k1 + 8]  = acr - bdr; vi[k1 + 8]  = aci - bdi;
        if (DIR < 0) {
            vr[k1 + 4]  = asr + bsi; vi[k1 + 4]  = asi - bsr;
            vr[k1 + 12] = asr - bsi; vi[k1 + 12] = asi + bsr;
        } else {
            vr[k1 + 4]  = asr - bsi; vi[k1 + 4]  = asi + bsr;
            vr[k1 + 12] = asr + bsi; vi[k1 + 12] = asi - bsr;
        }
    }
}

// Ping-pong radix-16 Stockham pass: src -> dst (no internal barrier; caller
// barriers between passes). w1 = per-thread base twiddle (direction-adjusted).
template<int DIR, int NS>
__device__ inline void fft_pass16_pp(const float2* __restrict__ src,
                                     float2* __restrict__ dst,
                                     float w1r, float w1i, int j) {
    float vr[16], vi[16];
#pragma unroll
    for (int r = 0; r < 16; ++r) {
        float2 x = src[SWZ(j + r * 256)];
        vr[r] = x.x; vi[r] = x.y;
    }
    if (NS > 1) {
        float wr[16], wi[16];
        wr[1] = w1r; wi[1] = w1i;
#pragma unroll
        for (int r = 2; r < 16; ++r)        // log-depth ladder: w^r = w^(r/2) * w^((r+1)/2)
            cmul(wr[r], wi[r], wr[r >> 1], wi[r >> 1], wr[(r + 1) >> 1], wi[(r + 1) >> 1]);
#pragma unroll
        for (int r = 1; r < 16; ++r) {
            float r0 = vr[r], i0 = vi[r];
            vr[r] = r0 * wr[r] - i0 * wi[r];
            vi[r] = r0 * wi[r] + i0 * wr[r];
        }
    }
    fft16<DIR>(vr, vi);
    int base = (j / NS) * (16 * NS) + (j & (NS - 1));
#pragma unroll
    for (int r = 0; r < 16; ++r)
        dst[SWZ(base + r * NS)] = make_float2(vr[r], vi[r]);
}

// 3 ping-pong passes: A -> B -> A -> B. Result in B (natural order, swizzled).
// 1 barrier per pass; caller barriers after loading A.
template<int DIR>
__device__ inline void fft4096_pp(float2* A, float2* Bu, float c2, float s2,
                                  float c3, float s3, int tid) {
    fft_pass16_pp<DIR, 1>(A, Bu, 1.f, 0.f, tid);  __syncthreads();
    fft_pass16_pp<DIR, 16>(Bu, A, c2, s2, tid);   __syncthreads();
    fft_pass16_pp<DIR, 256>(A, Bu, c3, s3, tid);  __syncthreads();
}

// Transpose+pack: q,k [B, L, 256] -> xT[b, c, l] = float2(q, k), c = h*32+d.
__global__ __launch_bounds__(256) void transpose_pack_kernel(const float4* __restrict__ q4,
                                                             const float4* __restrict__ k4,
                                                             float4* __restrict__ xT4) {
    __shared__ float qs[64][65];
    __shared__ float ks[64][65];
    int bid = blockIdx.x;             // b*256 + lt*4 + ct
    int ct = bid & 3;
    int lt = (bid >> 2) & 63;
    int b  = bid >> 8;
    int tid = threadIdx.x;
    int l0 = lt * 64, c0 = ct * 64;
    int cw = tid & 15;
    int rr = tid >> 4;
#pragma unroll
    for (int it = 0; it < 4; ++it) {
        int row = it * 16 + rr;       // l_local
        size_t g = (size_t)(b * 4096 + l0 + row) * 64u + (size_t)(c0 / 4 + cw);
        float4 qv = q4[g];
        float4 kv = k4[g];
        qs[row][cw * 4 + 0] = qv.x; qs[row][cw * 4 + 1] = qv.y;
        qs[row][cw * 4 + 2] = qv.z; qs[row][cw * 4 + 3] = qv.w;
        ks[row][cw * 4 + 0] = kv.x; ks[row][cw * 4 + 1] = kv.y;
        ks[row][cw * 4 + 2] = kv.z; ks[row][cw * 4 + 3] = kv.w;
    }
    __syncthreads();
    int a = tid & 31;                 // l-pair index (2 l per thread)
    int cb = tid >> 5;
#pragma unroll
    for (int it = 0; it < 8; ++it) {
        int cc = it * 8 + cb;         // c_local
        float4 o;
        o.x = qs[2 * a][cc];     o.y = ks[2 * a][cc];
        o.z = qs[2 * a + 1][cc]; o.w = ks[2 * a + 1][cc];
        xT4[(size_t)(b * 256 + c0 + cc) * 2048u + (size_t)(l0 / 2 + a)] = o;
    }
}

// Spectral product for an f-pair layout: thread t handles f0 = 2*tid+512*t.
__device__ inline void spd_pair_accum(const float2* Z, float4* acc, float& accny, int tid) {
#pragma unroll
    for (int t = 0; t < 4; ++t) {
        int f0 = 2 * tid + 512 * t;
        float2 za = Z[SWZ(f0)];
        float2 zb = Z[SWZ(f0 + 1)];
        float2 ma = Z[SWZ((4096 - f0) & 4095)];
        float2 mb = Z[SWZ(4095 - f0)];
        // elem 0: z1=za, z2=ma
        float qr = za.x + ma.x, qi = za.y - ma.y;
        float kr = za.y + ma.y, ki = za.x - ma.x;
        acc[t].x += 0.25f * (qr * kr - qi * ki);
        acc[t].y += 0.25f * (qr * ki + qi * kr);
        // elem 1: z1=zb, z2=mb
        qr = zb.x + mb.x; qi = zb.y - mb.y;
        kr = zb.y + mb.y; ki = zb.x - mb.x;
        acc[t].z += 0.25f * (qr * kr - qi * ki);
        acc[t].w += 0.25f * (qr * ki + qi * kr);
    }
    float2 zn = Z[SWZ(2048)];          // broadcast read
    accny += zn.x * zn.y;              // Q_nyq * K_nyq (both real)
}

// K1 fast: one block per (b, column-pair p). 2 sequential FFTs (ping-pong,
// 4 barriers each), register-accumulated product. 64 KB LDS, 2 blocks/CU.
__global__ __launch_bounds__(256) void fwd_spd_fast(const float2* __restrict__ xT,
                                                    float2* __restrict__ spd_d) {
    __shared__ float2 A[4096], Bu[4096];   // 64 KB
    int bid = blockIdx.x;                  // b*128 + p
    int tid = threadIdx.x;
    int b = bid >> 7, p = bid & 127;
    const float TWO_PI = 6.2831853071795864769f;
    float ang2 = TWO_PI * (float)((tid & 15) * 16) * (1.0f / 4096.0f);
    float ang3 = TWO_PI * (float)tid * (1.0f / 4096.0f);
    float c2 = cosf(ang2), s2 = sinf(ang2);
    float c3 = cosf(ang3), s3 = sinf(ang3);
    float4 acc[4];
#pragma unroll
    for (int t = 0; t < 4; ++t) acc[t] = make_float4(0.f, 0.f, 0.f, 0.f);
    float accny = 0.f;
#pragma unroll
    for (int cc = 0; cc < 2; ++cc) {
        // A is free here: pass3 of the previous FFT finished all A-reads
        // before its barrier; product reads only Bu.
        const float4* src4 = (const float4*)(xT + (size_t)(b * 256 + p * 2 + cc) * 4096u);
#pragma unroll
        for (int t = 0; t < 8; ++t) {
            float4 x = src4[tid + t * 256];
            int n = 2 * (tid + t * 256);
            A[SWZ(n)]     = make_float2(x.x, x.y);
            A[SWZ(n + 1)] = make_float2(x.z, x.w);
        }
        __syncthreads();
        fft4096_pp<-1>(A, Bu, c2, -s2, c3, -s3, tid);
        spd_pair_accum(Bu, acc, accny, tid);
    }
    float4* dst4 = (float4*)(spd_d + (size_t)bid * SLICE);
#pragma unroll
    for (int t = 0; t < 4; ++t) dst4[tid + t * 256] = acc[t];
    if (tid == 0) spd_d[(size_t)bid * SLICE + 2048] = make_float2(accny, 0.f);
}

// K1 slow fallback: strided loads straight from q,k; same ping-pong FFT.
__global__ __launch_bounds__(256) void fwd_spd_slow(const float* __restrict__ q,
                                                    const float* __restrict__ k,
                                                    float2* __restrict__ spd_d) {
    __shared__ float2 A[4096], Bu[4096];
    int bid = blockIdx.x;                 // b*128 + p
    int tid = threadIdx.x;
    int b = bid >> 7, p = bid & 127;
    const float TWO_PI = 6.2831853071795864769f;
    float ang2 = TWO_PI * (float)((tid & 15) * 16) * (1.0f / 4096.0f);
    float ang3 = TWO_PI * (float)tid * (1.0f / 4096.0f);
    float c2 = cosf(ang2), s2 = sinf(ang2);
    float c3 = cosf(ang3), s3 = sinf(ang3);
    float4 acc[4];
#pragma unroll
    for (int t = 0; t < 4; ++t) acc[t] = make_float4(0.f, 0.f, 0.f, 0.f);
    float accny = 0.f;
#pragma unroll
    for (int cc = 0; cc < 2; ++cc) {
        size_t base = (size_t)b * 1048576u + (size_t)(p * 2 + cc);
#pragma unroll
        for (int t = 0; t < 16; ++t) {
            int n = tid + t * 256;
            A[SWZ(n)] = make_float2(q[base + (size_t)n * 256u], k[base + (size_t)n * 256u]);
        }
        __syncthreads();
        fft4096_pp<-1>(A, Bu, c2, -s2, c3, -s3, tid);
        spd_pair_accum(Bu, acc, accny, tid);
    }
    float4* dst4 = (float4*)(spd_d + (size_t)bid * SLICE);
#pragma unroll
    for (int t = 0; t < 4; ++t) dst4[tid + t * 256] = acc[t];
    if (tid == 0) spd_d[(size_t)bid * SLICE + 2048] = make_float2(accny, 0.f);
}

// K2: one block per (b,h). Fused d-reduce (16 slices, float4), mirror Hermitian
// spectrum, inverse ping-pong FFT (x 1/N), register top-8, softmax.
__global__ __launch_bounds__(256) void ifft_topk_kernel(const float2* __restrict__ spd_d,
                                                        float* __restrict__ wout,
                                                        int* __restrict__ dout) {
    __shared__ float2 A[4096], Bu[4096];
    __shared__ float rv[8][4];
    __shared__ int   ri[8][4];
    int bh = blockIdx.x;
    int b = bh >> 3, h = bh & 7;
    int tid = threadIdx.x;
    const float TWO_PI = 6.2831853071795864769f;
    float ang2 = TWO_PI * (float)((tid & 15) * 16) * (1.0f / 4096.0f);
    float ang3 = TWO_PI * (float)tid * (1.0f / 4096.0f);
    float c2 = cosf(ang2), s2 = sinf(ang2);
    float c3 = cosf(ang3), s3 = sinf(ang3);
    const float sc = 1.0f / 4096.0f;
    const float2* base = spd_d + (size_t)(b * 128 + h * 16) * SLICE;
    const float4* base4 = (const float4*)base;
#pragma unroll
    for (int t = 0; t < 4; ++t) {
        int f0 = 2 * tid + 512 * t;
        float4 a = make_float4(0.f, 0.f, 0.f, 0.f);
#pragma unroll
        for (int s = 0; s < 16; ++s) {
            float4 x = base4[(size_t)s * (SLICE / 2) + (size_t)(tid + 256 * t)];
            a.x += x.x; a.y += x.y; a.z += x.z; a.w += x.w;
        }
        float r0 = a.x * sc, i0 = a.y * sc;
        float r1 = a.z * sc, i1 = a.w * sc;
        A[SWZ(f0)]     = make_float2(r0, i0);
        A[SWZ(f0 + 1)] = make_float2(r1, i1);
        if (f0 > 0) A[SWZ(4096 - f0)] = make_float2(r0, -i0);
        A[SWZ(4095 - f0)] = make_float2(r1, -i1);
    }
    if (tid == 0) {
        float ny = 0.f;
#pragma unroll
        for (int s = 0; s < 16; ++s) ny += base[(size_t)s * SLICE + 2048].x;
        A[SWZ(2048)] = make_float2(ny * sc, 0.f);
    }
    __syncthreads();
    fft4096_pp<1>(A, Bu, c2, s2, c3, s3, tid);
    // corr[tau] = Bu[SWZ(tau)].x -> registers
    float cv[16];
#pragma unroll
    for (int t = 0; t < 16; ++t) cv[t] = Bu[SWZ(tid + t * 256)].x;

    int lane = tid & 63, wid = tid >> 6;
    float topv[8]; int topi[8];
    for (int kk = 0; kk < 8; ++kk) {
        float best = -3.0e38f; int bi = 0;
#pragma unroll
        for (int t = 0; t < 16; ++t) {
            int f = tid + t * 256;
            if (cv[t] > best) { best = cv[t]; bi = f; }   // strict > keeps lowest f
        }
#pragma unroll
        for (int off = 32; off > 0; off >>= 1) {
            float ov = __shfl_xor(best, off, 64);
            int   oi = __shfl_xor(bi, off, 64);
            if (ov > best || (ov == best && oi < bi)) { best = ov; bi = oi; }
        }
        if (lane == 0) { rv[kk][wid] = best; ri[kk][wid] = bi; }
        __syncthreads();
        float fb = rv[kk][0]; int fi = ri[kk][0];
#pragma unroll
        for (int w = 1; w < 4; ++w) {
            float ov = rv[kk][w]; int oi = ri[kk][w];
            if (ov > fb || (ov == fb && oi < fi)) { fb = ov; fi = oi; }
        }
        topv[kk] = fb; topi[kk] = fi;
        if (tid == (fi & 255)) {              // owner clears winner (static reg idx)
            int t_owner = fi >> 8;
#pragma unroll
            for (int t = 0; t < 16; ++t)
                if (t == t_owner) cv[t] = -3.0e38f;
        }
    }
    if (tid == 0) {
        float mx = topv[0];
        float e[8], s = 0.0f;
#pragma unroll
        for (int kk = 0; kk < 8; ++kk) { e[kk] = expf(topv[kk] - mx); s += e[kk]; }
        float inv = 1.0f / s;
#pragma unroll
        for (int kk = 0; kk < 8; ++kk) {
            wout[bh * 8 + kk] = e[kk] * inv;
            dout[bh * 8 + kk] = topi[kk];
        }
    }
}

// K3: b-major grid (b = blk & 7 -> per-XCD L2 residency of v[b], 4 MiB).
// One block per 16 l's; thread = (lq, c4), 4 reps; nontemporal out stores.
__global__ __launch_bounds__(256) void agg_kernel(const float4* __restrict__ v4,
                                                  const float* __restrict__ w,
                                                  const int* __restrict__ dl,
                                                  float4* __restrict__ out4) {
    __shared__ float sw[64];
    __shared__ int   sd[64];
    int blk = blockIdx.x;              // lg*8 + b  (b fastest -> XCD round-robin)
    int b = blk & 7, lg = blk >> 3;    // lg in [0,256), 16 l's each
    int tid = threadIdx.x;
    if (tid < 64) {
        int h = tid >> 3, kk = tid & 7;
        sw[tid] = w[(b * 8 + h) * 8 + kk];
        sd[tid] = dl[(b * 8 + h) * 8 + kk];
    }
    __syncthreads();
    int lq = tid >> 6;                 // 0..3
    int c4 = tid & 63;                 // float4 index over 256 floats
    int h  = c4 >> 3;
    float w_[8]; int d_[8];
#pragma unroll
    for (int kk = 0; kk < 8; ++kk) { w_[kk] = sw[h * 8 + kk]; d_[kk] = sd[h * 8 + kk]; }
#pragma unroll
    for (int rep = 0; rep < 4; ++rep) {
        int l = lg * 16 + rep * 4 + lq;
        float4 acc = make_float4(0.f, 0.f, 0.f, 0.f);
#pragma unroll
        for (int kk = 0; kk < 8; ++kk) {
            int l2 = (l + d_[kk]) & 4095;
            float4 x = v4[(size_t)(b * 4096 + l2) * 64u + (size_t)c4];
            acc.x += w_[kk] * x.x; acc.y += w_[kk] * x.y;
            acc.z += w_[kk] * x.z; acc.w += w_[kk] * x.w;
        }
        nfloat4 nv = {acc.x, acc.y, acc.z, acc.w};
        __builtin_nontemporal_store(nv,
            (nfloat4*)&out4[(size_t)(b * 4096 + l) * 64u + (size_t)c4]);
    }
}

extern "C" void kernel_launch(void* const* d_in, const int* in_sizes, int n_in,
                              void* d_out, int out_size, void* d_ws, size_t ws_size,
                              hipStream_t stream) {
    const float* q = (const float*)d_in[0];
    const float* k = (const float*)d_in[1];
    const float* v = (const float*)d_in[2];
    float* ws  = (float*)d_ws;
    // d_out doubles as spd_d scratch: 1024 slices x SLICE float2 = 16.8 MB
    // (out is 33.5 MB; agg fully rewrites it last).
    float2* spd_d = (float2*)d_out;

    const size_t XT_FLOATS = 16777216u;     // xT: 2048 slices x 4096 complex
    const size_t FAST_FLOATS = XT_FLOATS + 1024u;
    bool fast = ws_size >= FAST_FLOATS * sizeof(float);

    if (fast) {
        float* wbuf = ws + XT_FLOATS;       // 512 floats
        int*   dbuf = (int*)(wbuf + 512);   // 512 ints
        transpose_pack_kernel<<<2048, 256, 0, stream>>>((const float4*)q, (const float4*)k,
                                                        (float4*)ws);
        fwd_spd_fast<<<1024, 256, 0, stream>>>((const float2*)ws, spd_d);
        ifft_topk_kernel<<<64, 256, 0, stream>>>(spd_d, wbuf, dbuf);
        agg_kernel<<<2048, 256, 0, stream>>>((const float4*)v, wbuf, dbuf, (float4*)d_out);
    } else {
        float* wbuf = ws;
        int*   dbuf = (int*)(wbuf + 512);
        fwd_spd_slow<<<1024, 256, 0, stream>>>(q, k, spd_d);
        ifft_topk_kernel<<<64, 256, 0, stream>>>(spd_d, wbuf, dbuf);
        agg_kernel<<<2048, 256, 0, stream>>>((const float4*)v, wbuf, dbuf, (float4*)d_out);
    }
}

// Round 14
// 85.432 us; speedup vs baseline: 1.4129x; 1.0182x over previous
//
#include <hip/hip_runtime.h>
#include <hip/hip_bf16.h>

// AutoCorrelation (Autoformer): FFT-based circular cross-correlation,
// top-8 delays, softmax weights, rolled-value aggregation.
// B=8, L=4096, H=8, D=32, K=8. Layout [B,L,H,D]: idx = b*1048576 + l*256 + h*32 + d.
//
// R13: R12 (ping-pong FFT, 4 barriers) + fwd_spd does 4 columns/block
//      (512 blocks = one full 2-per-CU round; spd_d halved to 8.4 MB;
//      ifft d-reduce 8 slices) + agg 32 l's/block (8 reps, more ILP).

#define SWZ(i) ((i) ^ (((i) >> 4) & 15))   // float2-index swizzle: pos ^= row&15
#define SLICE 2056                          // float2 per spd_d slice (breaks pow2 aliasing)

typedef float nfloat4 __attribute__((ext_vector_type(4)));   // native vec for builtins

__device__ inline void cmul(float& outr, float& outi, float ar, float ai, float br, float bi) {
    outr = ar * br - ai * bi;
    outi = ar * bi + ai * br;
}

// 16-point DFT in registers. DIR=-1 forward, +1 inverse (no 1/N scale).
template<int DIR>
__device__ inline void fft16(float* vr, float* vi) {
    const float C1 = 0.92387953251128675613f;  // cos(pi/8)
    const float S1 = 0.38268343236508977173f;  // sin(pi/8)
    const float R2 = 0.70710678118654752440f;  // sqrt(2)/2
    float ur[16], ui[16];
#pragma unroll
    for (int n2 = 0; n2 < 4; ++n2) {
        float ar = vr[n2],      ai = vi[n2];
        float br = vr[n2 + 4],  bi = vi[n2 + 4];
        float cr = vr[n2 + 8],  ci = vi[n2 + 8];
        float dr = vr[n2 + 12], di = vi[n2 + 12];
        float acr = ar + cr, aci = ai + ci;
        float asr = ar - cr, asi = ai - ci;
        float bdr = br + dr, bdi = bi + di;
        float bsr = br - dr, bsi = bi - di;
        ur[0 + n2]  = acr + bdr; ui[0 + n2]  = aci + bdi;
        ur[8 + n2]  = acr - bdr; ui[8 + n2]  = aci - bdi;
        if (DIR < 0) {
            ur[4 + n2]  = asr + bsi; ui[4 + n2]  = asi - bsr;
            ur[12 + n2] = asr - bsi; ui[12 + n2] = asi + bsr;
        } else {
            ur[4 + n2]  = asr - bsi; ui[4 + n2]  = asi + bsr;
            ur[12 + n2] = asr + bsi; ui[12 + n2] = asi - bsr;
        }
    }
#pragma unroll
    for (int k1 = 1; k1 < 4; ++k1) {
#pragma unroll
        for (int n2 = 1; n2 < 4; ++n2) {
            int e = k1 * n2;        // in {1,2,3,4,6,9}
            float c, s;
            if (e == 1)      { c = C1;  s = S1; }
            else if (e == 2) { c = R2;  s = R2; }
            else if (e == 3) { c = S1;  s = C1; }
            else if (e == 4) { c = 0.f; s = 1.f; }
            else if (e == 6) { c = -R2; s = R2; }
            else             { c = -C1; s = -S1; }   // e == 9
            int idx = k1 * 4 + n2;
            float r0 = ur[idx], i0 = ui[idx];
            if (DIR < 0) { ur[idx] = r0 * c + i0 * s; ui[idx] = i0 * c - r0 * s; }
            else         { ur[idx] = r0 * c - i0 * s; ui[idx] = i0 * c + r0 * s; }
        }
    }
#pragma unroll
    for (int k1 = 0; k1 < 4; ++k1) {
        float ar = ur[k1 * 4 + 0], ai = ui[k1 * 4 + 0];
        float br = ur[k1 * 4 + 1], bi = ui[k1 * 4 + 1];
        float cr = ur[k1 * 4 + 2], ci = ui[k1 * 4 + 2];
        float dr = ur[k1 * 4 + 3], di = ui[k1 * 4 + 3];
        float acr = ar + cr, aci = ai + ci;
        float asr = ar - cr, asi = ai - ci;
        float bdr = br + dr, bdi = bi + di;
        float bsr = br - dr, bsi = bi - di;
        vr[k1]      = acr + bdr; vi[k1]      = aci + bdi;
        vr[k1 + 8]  = acr - bdr; vi[k1 + 8]  = aci - bdi;
        if (DIR < 0) {
            vr[k1 + 4]  = asr + bsi; vi[k1 + 4]  = asi - bsr;
            vr[k1 + 12] = asr - bsi; vi[k1 + 12] = asi + bsr;
        } else {
            vr[k1 + 4]  = asr - bsi; vi[k1 + 4]  = asi + bsr;
            vr[k1 + 12] = asr + bsi; vi[k1 + 12] = asi - bsr;
        }
    }
}

// Ping-pong radix-16 Stockham pass: src -> dst (no internal barrier; caller
// barriers between passes). w1 = per-thread base twiddle (direction-adjusted).
template<int DIR, int NS>
__device__ inline void fft_pass16_pp(const float2* __restrict__ src,
                                     float2* __restrict__ dst,
                                     float w1r, float w1i, int j) {
    float vr[16], vi[16];
#pragma unroll
    for (int r = 0; r < 16; ++r) {
        float2 x = src[SWZ(j + r * 256)];
        vr[r] = x.x; vi[r] = x.y;
    }
    if (NS > 1) {
        float wr[16], wi[16];
        wr[1] = w1r; wi[1] = w1i;
#pragma unroll
        for (int r = 2; r < 16; ++r)        // log-depth ladder: w^r = w^(r/2) * w^((r+1)/2)
            cmul(wr[r], wi[r], wr[r >> 1], wi[r >> 1], wr[(r + 1) >> 1], wi[(r + 1) >> 1]);
#pragma unroll
        for (int r = 1; r < 16; ++r) {
            float r0 = vr[r], i0 = vi[r];
            vr[r] = r0 * wr[r] - i0 * wi[r];
            vi[r] = r0 * wi[r] + i0 * wr[r];
        }
    }
    fft16<DIR>(vr, vi);
    int base = (j / NS) * (16 * NS) + (j & (NS - 1));
#pragma unroll
    for (int r = 0; r < 16; ++r)
        dst[SWZ(base + r * NS)] = make_float2(vr[r], vi[r]);
}

// 3 ping-pong passes: A -> B -> A -> B. Result in B (natural order, swizzled).
template<int DIR>
__device__ inline void fft4096_pp(float2* A, float2* Bu, float c2, float s2,
                                  float c3, float s3, int tid) {
    fft_pass16_pp<DIR, 1>(A, Bu, 1.f, 0.f, tid);  __syncthreads();
    fft_pass16_pp<DIR, 16>(Bu, A, c2, s2, tid);   __syncthreads();
    fft_pass16_pp<DIR, 256>(A, Bu, c3, s3, tid);  __syncthreads();
}

// Transpose+pack: q,k [B, L, 256] -> xT[b, c, l] = float2(q, k), c = h*32+d.
__global__ __launch_bounds__(256) void transpose_pack_kernel(const float4* __restrict__ q4,
                                                             const float4* __restrict__ k4,
                                                             float4* __restrict__ xT4) {
    __shared__ float qs[64][65];
    __shared__ float ks[64][65];
    int bid = blockIdx.x;             // b*256 + lt*4 + ct
    int ct = bid & 3;
    int lt = (bid >> 2) & 63;
    int b  = bid >> 8;
    int tid = threadIdx.x;
    int l0 = lt * 64, c0 = ct * 64;
    int cw = tid & 15;
    int rr = tid >> 4;
#pragma unroll
    for (int it = 0; it < 4; ++it) {
        int row = it * 16 + rr;       // l_local
        size_t g = (size_t)(b * 4096 + l0 + row) * 64u + (size_t)(c0 / 4 + cw);
        float4 qv = q4[g];
        float4 kv = k4[g];
        qs[row][cw * 4 + 0] = qv.x; qs[row][cw * 4 + 1] = qv.y;
        qs[row][cw * 4 + 2] = qv.z; qs[row][cw * 4 + 3] = qv.w;
        ks[row][cw * 4 + 0] = kv.x; ks[row][cw * 4 + 1] = kv.y;
        ks[row][cw * 4 + 2] = kv.z; ks[row][cw * 4 + 3] = kv.w;
    }
    __syncthreads();
    int a = tid & 31;                 // l-pair index (2 l per thread)
    int cb = tid >> 5;
#pragma unroll
    for (int it = 0; it < 8; ++it) {
        int cc = it * 8 + cb;         // c_local
        float4 o;
        o.x = qs[2 * a][cc];     o.y = ks[2 * a][cc];
        o.z = qs[2 * a + 1][cc]; o.w = ks[2 * a + 1][cc];
        xT4[(size_t)(b * 256 + c0 + cc) * 2048u + (size_t)(l0 / 2 + a)] = o;
    }
}

// Spectral product for an f-pair layout: thread t handles f0 = 2*tid+512*t.
__device__ inline void spd_pair_accum(const float2* Z, float4* acc, float& accny, int tid) {
#pragma unroll
    for (int t = 0; t < 4; ++t) {
        int f0 = 2 * tid + 512 * t;
        float2 za = Z[SWZ(f0)];
        float2 zb = Z[SWZ(f0 + 1)];
        float2 ma = Z[SWZ((4096 - f0) & 4095)];
        float2 mb = Z[SWZ(4095 - f0)];
        // elem 0: z1=za, z2=ma
        float qr = za.x + ma.x, qi = za.y - ma.y;
        float kr = za.y + ma.y, ki = za.x - ma.x;
        acc[t].x += 0.25f * (qr * kr - qi * ki);
        acc[t].y += 0.25f * (qr * ki + qi * kr);
        // elem 1: z1=zb, z2=mb
        qr = zb.x + mb.x; qi = zb.y - mb.y;
        kr = zb.y + mb.y; ki = zb.x - mb.x;
        acc[t].z += 0.25f * (qr * kr - qi * ki);
        acc[t].w += 0.25f * (qr * ki + qi * kr);
    }
    float2 zn = Z[SWZ(2048)];          // broadcast read
    accny += zn.x * zn.y;              // Q_nyq * K_nyq (both real)
}

// K1 fast: one block per (b, column-quad p). 4 sequential FFTs (ping-pong,
// 4 barriers each), register-accumulated product, one slice store.
// 64 KB LDS -> 2 blocks/CU; 512 blocks = exactly one full dispatch round.
__global__ __launch_bounds__(256) void fwd_spd_fast(const float2* __restrict__ xT,
                                                    float2* __restrict__ spd_d) {
    __shared__ float2 A[4096], Bu[4096];   // 64 KB
    int bid = blockIdx.x;                  // b*64 + p
    int tid = threadIdx.x;
    int b = bid >> 6, p = bid & 63;
    const float TWO_PI = 6.2831853071795864769f;
    float ang2 = TWO_PI * (float)((tid & 15) * 16) * (1.0f / 4096.0f);
    float ang3 = TWO_PI * (float)tid * (1.0f / 4096.0f);
    float c2 = cosf(ang2), s2 = sinf(ang2);
    float c3 = cosf(ang3), s3 = sinf(ang3);
    float4 acc[4];
#pragma unroll
    for (int t = 0; t < 4; ++t) acc[t] = make_float4(0.f, 0.f, 0.f, 0.f);
    float accny = 0.f;
#pragma unroll
    for (int cc = 0; cc < 4; ++cc) {
        // A is free here: pass3 finished all A-reads before its barrier;
        // the product reads only Bu.
        const float4* src4 = (const float4*)(xT + (size_t)(b * 256 + p * 4 + cc) * 4096u);
#pragma unroll
        for (int t = 0; t < 8; ++t) {
            float4 x = src4[tid + t * 256];
            int n = 2 * (tid + t * 256);
            A[SWZ(n)]     = make_float2(x.x, x.y);
            A[SWZ(n + 1)] = make_float2(x.z, x.w);
        }
        __syncthreads();
        fft4096_pp<-1>(A, Bu, c2, -s2, c3, -s3, tid);
        spd_pair_accum(Bu, acc, accny, tid);
        if (cc < 3) __syncthreads();       // Bu reads done before next FFT writes
    }
    float4* dst4 = (float4*)(spd_d + (size_t)bid * SLICE);
#pragma unroll
    for (int t = 0; t < 4; ++t) dst4[tid + t * 256] = acc[t];
    if (tid == 0) spd_d[(size_t)bid * SLICE + 2048] = make_float2(accny, 0.f);
}

// K1 slow fallback: strided loads straight from q,k; same structure.
__global__ __launch_bounds__(256) void fwd_spd_slow(const float* __restrict__ q,
                                                    const float* __restrict__ k,
                                                    float2* __restrict__ spd_d) {
    __shared__ float2 A[4096], Bu[4096];
    int bid = blockIdx.x;                 // b*64 + p
    int tid = threadIdx.x;
    int b = bid >> 6, p = bid & 63;
    const float TWO_PI = 6.2831853071795864769f;
    float ang2 = TWO_PI * (float)((tid & 15) * 16) * (1.0f / 4096.0f);
    float ang3 = TWO_PI * (float)tid * (1.0f / 4096.0f);
    float c2 = cosf(ang2), s2 = sinf(ang2);
    float c3 = cosf(ang3), s3 = sinf(ang3);
    float4 acc[4];
#pragma unroll
    for (int t = 0; t < 4; ++t) acc[t] = make_float4(0.f, 0.f, 0.f, 0.f);
    float accny = 0.f;
#pragma unroll
    for (int cc = 0; cc < 4; ++cc) {
        size_t base = (size_t)b * 1048576u + (size_t)(p * 4 + cc);
#pragma unroll
        for (int t = 0; t < 16; ++t) {
            int n = tid + t * 256;
            A[SWZ(n)] = make_float2(q[base + (size_t)n * 256u], k[base + (size_t)n * 256u]);
        }
        __syncthreads();
        fft4096_pp<-1>(A, Bu, c2, -s2, c3, -s3, tid);
        spd_pair_accum(Bu, acc, accny, tid);
        if (cc < 3) __syncthreads();
    }
    float4* dst4 = (float4*)(spd_d + (size_t)bid * SLICE);
#pragma unroll
    for (int t = 0; t < 4; ++t) dst4[tid + t * 256] = acc[t];
    if (tid == 0) spd_d[(size_t)bid * SLICE + 2048] = make_float2(accny, 0.f);
}

// K2: one block per (b,h). Fused d-reduce (8 slices, float4), mirror Hermitian
// spectrum, inverse ping-pong FFT (x 1/N), register top-8, softmax.
__global__ __launch_bounds__(256) void ifft_topk_kernel(const float2* __restrict__ spd_d,
                                                        float* __restrict__ wout,
                                                        int* __restrict__ dout) {
    __shared__ float2 A[4096], Bu[4096];
    __shared__ float rv[8][4];
    __shared__ int   ri[8][4];
    int bh = blockIdx.x;
    int b = bh >> 3, h = bh & 7;
    int tid = threadIdx.x;
    const float TWO_PI = 6.2831853071795864769f;
    float ang2 = TWO_PI * (float)((tid & 15) * 16) * (1.0f / 4096.0f);
    float ang3 = TWO_PI * (float)tid * (1.0f / 4096.0f);
    float c2 = cosf(ang2), s2 = sinf(ang2);
    float c3 = cosf(ang3), s3 = sinf(ang3);
    const float sc = 1.0f / 4096.0f;
    const float2* base = spd_d + (size_t)(b * 64 + h * 8) * SLICE;
    const float4* base4 = (const float4*)base;
#pragma unroll
    for (int t = 0; t < 4; ++t) {
        int f0 = 2 * tid + 512 * t;
        float4 a = make_float4(0.f, 0.f, 0.f, 0.f);
#pragma unroll
        for (int s = 0; s < 8; ++s) {
            float4 x = base4[(size_t)s * (SLICE / 2) + (size_t)(tid + 256 * t)];
            a.x += x.x; a.y += x.y; a.z += x.z; a.w += x.w;
        }
        float r0 = a.x * sc, i0 = a.y * sc;
        float r1 = a.z * sc, i1 = a.w * sc;
        A[SWZ(f0)]     = make_float2(r0, i0);
        A[SWZ(f0 + 1)] = make_float2(r1, i1);
        if (f0 > 0) A[SWZ(4096 - f0)] = make_float2(r0, -i0);
        A[SWZ(4095 - f0)] = make_float2(r1, -i1);
    }
    if (tid == 0) {
        float ny = 0.f;
#pragma unroll
        for (int s = 0; s < 8; ++s) ny += base[(size_t)s * SLICE + 2048].x;
        A[SWZ(2048)] = make_float2(ny * sc, 0.f);
    }
    __syncthreads();
    fft4096_pp<1>(A, Bu, c2, s2, c3, s3, tid);
    // corr[tau] = Bu[SWZ(tau)].x -> registers
    float cv[16];
#pragma unroll
    for (int t = 0; t < 16; ++t) cv[t] = Bu[SWZ(tid + t * 256)].x;

    int lane = tid & 63, wid = tid >> 6;
    float topv[8]; int topi[8];
    for (int kk = 0; kk < 8; ++kk) {
        float best = -3.0e38f; int bi = 0;
#pragma unroll
        for (int t = 0; t < 16; ++t) {
            int f = tid + t * 256;
            if (cv[t] > best) { best = cv[t]; bi = f; }   // strict > keeps lowest f
        }
#pragma unroll
        for (int off = 32; off > 0; off >>= 1) {
            float ov = __shfl_xor(best, off, 64);
            int   oi = __shfl_xor(bi, off, 64);
            if (ov > best || (ov == best && oi < bi)) { best = ov; bi = oi; }
        }
        if (lane == 0) { rv[kk][wid] = best; ri[kk][wid] = bi; }
        __syncthreads();
        float fb = rv[kk][0]; int fi = ri[kk][0];
#pragma unroll
        for (int w = 1; w < 4; ++w) {
            float ov = rv[kk][w]; int oi = ri[kk][w];
            if (ov > fb || (ov == fb && oi < fi)) { fb = ov; fi = oi; }
        }
        topv[kk] = fb; topi[kk] = fi;
        if (tid == (fi & 255)) {              // owner clears winner (static reg idx)
            int t_owner = fi >> 8;
#pragma unroll
            for (int t = 0; t < 16; ++t)
                if (t == t_owner) cv[t] = -3.0e38f;
        }
    }
    if (tid == 0) {
        float mx = topv[0];
        float e[8], s = 0.0f;
#pragma unroll
        for (int kk = 0; kk < 8; ++kk) { e[kk] = expf(topv[kk] - mx); s += e[kk]; }
        float inv = 1.0f / s;
#pragma unroll
        for (int kk = 0; kk < 8; ++kk) {
            wout[bh * 8 + kk] = e[kk] * inv;
            dout[bh * 8 + kk] = topi[kk];
        }
    }
}

// K3: b-major grid (b = blk & 7 -> per-XCD L2 residency of v[b], 4 MiB).
// One block per 32 l's; thread = (lq, c4), 8 reps; nontemporal out stores.
__global__ __launch_bounds__(256) void agg_kernel(const float4* __restrict__ v4,
                                                  const float* __restrict__ w,
                                                  const int* __restrict__ dl,
                                                  float4* __restrict__ out4) {
    __shared__ float sw[64];
    __shared__ int   sd[64];
    int blk = blockIdx.x;              // lg*8 + b  (b fastest -> XCD round-robin)
    int b = blk & 7, lg = blk >> 3;    // lg in [0,128), 32 l's each
    int tid = threadIdx.x;
    if (tid < 64) {
        int h = tid >> 3, kk = tid & 7;
        sw[tid] = w[(b * 8 + h) * 8 + kk];
        sd[tid] = dl[(b * 8 + h) * 8 + kk];
    }
    __syncthreads();
    int lq = tid >> 6;                 // 0..3
    int c4 = tid & 63;                 // float4 index over 256 floats
    int h  = c4 >> 3;
    float w_[8]; int d_[8];
#pragma unroll
    for (int kk = 0; kk < 8; ++kk) { w_[kk] = sw[h * 8 + kk]; d_[kk] = sd[h * 8 + kk]; }
#pragma unroll
    for (int rep = 0; rep < 8; ++rep) {
        int l = lg * 32 + rep * 4 + lq;
        float4 acc = make_float4(0.f, 0.f, 0.f, 0.f);
#pragma unroll
        for (int kk = 0; kk < 8; ++kk) {
            int l2 = (l + d_[kk]) & 4095;
            float4 x = v4[(size_t)(b * 4096 + l2) * 64u + (size_t)c4];
            acc.x += w_[kk] * x.x; acc.y += w_[kk] * x.y;
            acc.z += w_[kk] * x.z; acc.w += w_[kk] * x.w;
        }
        nfloat4 nv = {acc.x, acc.y, acc.z, acc.w};
        __builtin_nontemporal_store(nv,
            (nfloat4*)&out4[(size_t)(b * 4096 + l) * 64u + (size_t)c4]);
    }
}

extern "C" void kernel_launch(void* const* d_in, const int* in_sizes, int n_in,
                              void* d_out, int out_size, void* d_ws, size_t ws_size,
                              hipStream_t stream) {
    const float* q = (const float*)d_in[0];
    const float* k = (const float*)d_in[1];
    const float* v = (const float*)d_in[2];
    float* ws  = (float*)d_ws;
    // d_out doubles as spd_d scratch: 512 slices x SLICE float2 = 8.4 MB
    // (out is 33.5 MB; agg fully rewrites it last).
    float2* spd_d = (float2*)d_out;

    const size_t XT_FLOATS = 16777216u;     // xT: 2048 slices x 4096 complex
    const size_t FAST_FLOATS = XT_FLOATS + 1024u;
    bool fast = ws_size >= FAST_FLOATS * sizeof(float);

    if (fast) {
        float* wbuf = ws + XT_FLOATS;       // 512 floats
        int*   dbuf = (int*)(wbuf + 512);   // 512 ints
        transpose_pack_kernel<<<2048, 256, 0, stream>>>((const float4*)q, (const float4*)k,
                                                        (float4*)ws);
        fwd_spd_fast<<<512, 256, 0, stream>>>((const float2*)ws, spd_d);
        ifft_topk_kernel<<<64, 256, 0, stream>>>(spd_d, wbuf, dbuf);
        agg_kernel<<<1024, 256, 0, stream>>>((const float4*)v, wbuf, dbuf, (float4*)d_out);
    } else {
        float* wbuf = ws;
        int*   dbuf = (int*)(wbuf + 512);
        fwd_spd_slow<<<512, 256, 0, stream>>>(q, k, spd_d);
        ifft_topk_kernel<<<64, 256, 0, stream>>>(spd_d, wbuf, dbuf);
        agg_kernel<<<1024, 256, 0, stream>>>((const float4*)v, wbuf, dbuf, (float4*)d_out);
    }
}

// Round 17
// 84.868 us; speedup vs baseline: 1.4223x; 1.0066x over previous
//
#include <hip/hip_runtime.h>
#include <hip/hip_bf16.h>

// AutoCorrelation (Autoformer): FFT-based circular cross-correlation,
// top-8 delays, softmax weights, rolled-value aggregation.
// B=8, L=4096, H=8, D=32, K=8. Layout [B,L,H,D]: idx = b*1048576 + l*256 + h*32 + d.
//
// R16: R14 design with the staging-offset bug FIXED (column stride is 2048
//      float4, not 1024 — R14/R15 read garbage for columns 1-3). Pre-swizzled
//      xT image + async global_load_lds width-16 staging (zero VGPR) + next
//      column's loads issued before the spectral product (latency hidden).

#define SWZ(i) ((i) ^ (((i) >> 4) & 15))   // float2-index swizzle: pos ^= row&15
#define SLICE 2056                          // float2 per spd_d slice (breaks pow2 aliasing)

typedef float nfloat4 __attribute__((ext_vector_type(4)));   // native vec for builtins

__device__ inline void cmul(float& outr, float& outi, float ar, float ai, float br, float bi) {
    outr = ar * br - ai * bi;
    outi = ar * bi + ai * br;
}

// 16-point DFT in registers. DIR=-1 forward, +1 inverse (no 1/N scale).
template<int DIR>
__device__ inline void fft16(float* vr, float* vi) {
    const float C1 = 0.92387953251128675613f;  // cos(pi/8)
    const float S1 = 0.38268343236508977173f;  // sin(pi/8)
    const float R2 = 0.70710678118654752440f;  // sqrt(2)/2
    float ur[16], ui[16];
#pragma unroll
    for (int n2 = 0; n2 < 4; ++n2) {
        float ar = vr[n2],      ai = vi[n2];
        float br = vr[n2 + 4],  bi = vi[n2 + 4];
        float cr = vr[n2 + 8],  ci = vi[n2 + 8];
        float dr = vr[n2 + 12], di = vi[n2 + 12];
        float acr = ar + cr, aci = ai + ci;
        float asr = ar - cr, asi = ai - ci;
        float bdr = br + dr, bdi = bi + di;
        float bsr = br - dr, bsi = bi - di;
        ur[0 + n2]  = acr + bdr; ui[0 + n2]  = aci + bdi;
        ur[8 + n2]  = acr - bdr; ui[8 + n2]  = aci - bdi;
        if (DIR < 0) {
            ur[4 + n2]  = asr + bsi; ui[4 + n2]  = asi - bsr;
            ur[12 + n2] = asr - bsi; ui[12 + n2] = asi + bsr;
        } else {
            ur[4 + n2]  = asr - bsi; ui[4 + n2]  = asi + bsr;
            ur[12 + n2] = asr + bsi; ui[12 + n2] = asi - bsr;
        }
    }
#pragma unroll
    for (int k1 = 1; k1 < 4; ++k1) {
#pragma unroll
        for (int n2 = 1; n2 < 4; ++n2) {
            int e = k1 * n2;        // in {1,2,3,4,6,9}
            float c, s;
            if (e == 1)      { c = C1;  s = S1; }
            else if (e == 2) { c = R2;  s = R2; }
            else if (e == 3) { c = S1;  s = C1; }
            else if (e == 4) { c = 0.f; s = 1.f; }
            else if (e == 6) { c = -R2; s = R2; }
            else             { c = -C1; s = -S1; }   // e == 9
            int idx = k1 * 4 + n2;
            float r0 = ur[idx], i0 = ui[idx];
            if (DIR < 0) { ur[idx] = r0 * c + i0 * s; ui[idx] = i0 * c - r0 * s; }
            else         { ur[idx] = r0 * c - i0 * s; ui[idx] = i0 * c + r0 * s; }
        }
    }
#pragma unroll
    for (int k1 = 0; k1 < 4; ++k1) {
        float ar = ur[k1 * 4 + 0], ai = ui[k1 * 4 + 0];
        float br = ur[k1 * 4 + 1], bi = ui[k1 * 4 + 1];
        float cr = ur[k1 * 4 + 2], ci = ui[k1 * 4 + 2];
        float dr = ur[k1 * 4 + 3], di = ui[k1 * 4 + 3];
        float acr = ar + cr, aci = ai + ci;
        float asr = ar - cr, asi = ai - ci;
        float bdr = br + dr, bdi = bi + di;
        float bsr = br - dr, bsi = bi - di;
        vr[k1]      = acr + bdr; vi[k1]      = aci + bdi;
        vr[k1 + 8]  = acr - bdr; vi[k1 + 8]  = aci - bdi;
        if (DIR < 0) {
            vr[k1 + 4]  = asr + bsi; vi[k1 + 4]  = asi - bsr;
            vr[k1 + 12] = asr - bsi; vi[k1 + 12] = asi + bsr;
        } else {
            vr[k1 + 4]  = asr - bsi; vi[k1 + 4]  = asi + bsr;
            vr[k1 + 12] = asr + bsi; vi[k1 + 12] = asi - bsr;
        }
    }
}

// Ping-pong radix-16 Stockham pass: src -> dst (no internal barrier; caller
// barriers between passes). w1 = per-thread base twiddle (direction-adjusted).
template<int DIR, int NS>
__device__ inline void fft_pass16_pp(const float2* __restrict__ src,
                                     float2* __restrict__ dst,
                                     float w1r, float w1i, int j) {
    float vr[16], vi[16];
#pragma unroll
    for (int r = 0; r < 16; ++r) {
        float2 x = src[SWZ(j + r * 256)];
        vr[r] = x.x; vi[r] = x.y;
    }
    if (NS > 1) {
        float wr[16], wi[16];
        wr[1] = w1r; wi[1] = w1i;
#pragma unroll
        for (int r = 2; r < 16; ++r)        // log-depth ladder: w^r = w^(r/2) * w^((r+1)/2)
            cmul(wr[r], wi[r], wr[r >> 1], wi[r >> 1], wr[(r + 1) >> 1], wi[(r + 1) >> 1]);
#pragma unroll
        for (int r = 1; r < 16; ++r) {
            float r0 = vr[r], i0 = vi[r];
            vr[r] = r0 * wr[r] - i0 * wi[r];
            vi[r] = r0 * wi[r] + i0 * wr[r];
        }
    }
    fft16<DIR>(vr, vi);
    int base = (j / NS) * (16 * NS) + (j & (NS - 1));
#pragma unroll
    for (int r = 0; r < 16; ++r)
        dst[SWZ(base + r * NS)] = make_float2(vr[r], vi[r]);
}

// 3 ping-pong passes: A -> B -> A -> B. Result in B (natural order, swizzled).
template<int DIR>
__device__ inline void fft4096_pp(float2* A, float2* Bu, float c2, float s2,
                                  float c3, float s3, int tid) {
    fft_pass16_pp<DIR, 1>(A, Bu, 1.f, 0.f, tid);  __syncthreads();
    fft_pass16_pp<DIR, 16>(Bu, A, c2, s2, tid);   __syncthreads();
    fft_pass16_pp<DIR, 256>(A, Bu, c3, s3, tid);  __syncthreads();
}

// Transpose+pack: q,k [B, L, 256] -> xT_img[b, c, SWZ(l)] = float2(q, k).
// xT is a byte-exact LDS image (SWZ is an involution; permutes only within
// 128 B blocks, so wave writes still cover full cache lines).
__global__ __launch_bounds__(256) void transpose_pack_kernel(const float4* __restrict__ q4,
                                                             const float4* __restrict__ k4,
                                                             float4* __restrict__ xT4) {
    __shared__ float qs[64][65];
    __shared__ float ks[64][65];
    int bid = blockIdx.x;             // b*256 + lt*4 + ct
    int ct = bid & 3;
    int lt = (bid >> 2) & 63;
    int b  = bid >> 8;
    int tid = threadIdx.x;
    int l0 = lt * 64, c0 = ct * 64;
    int cw = tid & 15;
    int rr = tid >> 4;
#pragma unroll
    for (int it = 0; it < 4; ++it) {
        int row = it * 16 + rr;       // l_local
        size_t g = (size_t)(b * 4096 + l0 + row) * 64u + (size_t)(c0 / 4 + cw);
        float4 qv = q4[g];
        float4 kv = k4[g];
        qs[row][cw * 4 + 0] = qv.x; qs[row][cw * 4 + 1] = qv.y;
        qs[row][cw * 4 + 2] = qv.z; qs[row][cw * 4 + 3] = qv.w;
        ks[row][cw * 4 + 0] = kv.x; ks[row][cw * 4 + 1] = kv.y;
        ks[row][cw * 4 + 2] = kv.z; ks[row][cw * 4 + 3] = kv.w;
    }
    __syncthreads();
    int a = tid & 31;                 // l-pair index (2 l per thread)
    int cb = tid >> 5;
#pragma unroll
    for (int it = 0; it < 8; ++it) {
        int cc = it * 8 + cb;         // c_local
        float2 z0 = make_float2(qs[2 * a][cc],     ks[2 * a][cc]);      // l = l0+2a
        float2 z1 = make_float2(qs[2 * a + 1][cc], ks[2 * a + 1][cc]);  // l = l0+2a+1
        int n  = l0 + 2 * a;
        int sn = SWZ(n);              // SWZ(n+1) == sn^1 (n even)
        float4 o = (sn & 1) ? make_float4(z1.x, z1.y, z0.x, z0.y)
                            : make_float4(z0.x, z0.y, z1.x, z1.y);
        xT4[(size_t)(b * 256 + c0 + cc) * 2048u + (size_t)(sn >> 1)] = o;
    }
}

// Spectral product for an f-pair layout: thread t handles f0 = 2*tid+512*t.
__device__ inline void spd_pair_accum(const float2* Z, float4* acc, float& accny, int tid) {
#pragma unroll
    for (int t = 0; t < 4; ++t) {
        int f0 = 2 * tid + 512 * t;
        float2 za = Z[SWZ(f0)];
        float2 zb = Z[SWZ(f0 + 1)];
        float2 ma = Z[SWZ((4096 - f0) & 4095)];
        float2 mb = Z[SWZ(4095 - f0)];
        // elem 0: z1=za, z2=ma
        float qr = za.x + ma.x, qi = za.y - ma.y;
        float kr = za.y + ma.y, ki = za.x - ma.x;
        acc[t].x += 0.25f * (qr * kr - qi * ki);
        acc[t].y += 0.25f * (qr * ki + qi * kr);
        // elem 1: z1=zb, z2=mb
        qr = zb.x + mb.x; qi = zb.y - mb.y;
        kr = zb.y + mb.y; ki = zb.x - mb.x;
        acc[t].z += 0.25f * (qr * kr - qi * ki);
        acc[t].w += 0.25f * (qr * ki + qi * kr);
    }
    float2 zn = Z[SWZ(2048)];          // broadcast read
    accny += zn.x * zn.y;              // Q_nyq * K_nyq (both real)
}

// K1 fast: one block per (b, column-quad p). xT image staged via async
// global_load_lds (width 16, per-t wave-uniform base + lane*16 — legal);
// next column's loads issued before the spectral product (latency hidden).
// Column stride = 2048 float4 (4096 float2) — THE R14/R15 BUG, now fixed.
__global__ __launch_bounds__(256) void fwd_spd_fast(const float2* __restrict__ xT,
                                                    float2* __restrict__ spd_d) {
    __shared__ __align__(16) float2 A[4096];
    __shared__ __align__(16) float2 Bu[4096];   // 64 KB total
    int bid = blockIdx.x;                  // b*64 + p
    int tid = threadIdx.x;
    int b = bid >> 6, p = bid & 63;
    const float TWO_PI = 6.2831853071795864769f;
    float ang2 = TWO_PI * (float)((tid & 15) * 16) * (1.0f / 4096.0f);
    float ang3 = TWO_PI * (float)tid * (1.0f / 4096.0f);
    float c2 = cosf(ang2), s2 = sinf(ang2);
    float c3 = cosf(ang3), s3 = sinf(ang3);
    float4 acc[4];
#pragma unroll
    for (int t = 0; t < 4; ++t) acc[t] = make_float4(0.f, 0.f, 0.f, 0.f);
    float accny = 0.f;

    const float4* base4 = (const float4*)(xT + (size_t)(b * 256 + p * 4) * 4096u);
    // stage column 0 (column stride in float4 = 2048)
#pragma unroll
    for (int t = 0; t < 8; ++t)
        __builtin_amdgcn_global_load_lds((const uint32_t*)&base4[tid + t * 256],
                                         (uint32_t*)&A[2 * (tid + t * 256)], 16, 0, 0);
    __syncthreads();                       // drains vmcnt -> A ready

#pragma unroll
    for (int cc = 0; cc < 4; ++cc) {
        fft4096_pp<-1>(A, Bu, c2, -s2, c3, -s3, tid);   // ends with barrier; A free
        if (cc < 3) {
            const float4* src4 = base4 + (size_t)(cc + 1) * 2048u;   // FIXED stride
#pragma unroll
            for (int t = 0; t < 8; ++t)
                __builtin_amdgcn_global_load_lds((const uint32_t*)&src4[tid + t * 256],
                                                 (uint32_t*)&A[2 * (tid + t * 256)], 16, 0, 0);
        }
        spd_pair_accum(Bu, acc, accny, tid);            // overlaps the loads
        if (cc < 3) __syncthreads();       // drain loads + protect Bu
    }
    float4* dst4 = (float4*)(spd_d + (size_t)bid * SLICE);
#pragma unroll
    for (int t = 0; t < 4; ++t) dst4[tid + t * 256] = acc[t];
    if (tid == 0) spd_d[(size_t)bid * SLICE + 2048] = make_float2(accny, 0.f);
}

// K1 slow fallback: strided loads straight from q,k; same FFT structure.
__global__ __launch_bounds__(256) void fwd_spd_slow(const float* __restrict__ q,
                                                    const float* __restrict__ k,
                                                    float2* __restrict__ spd_d) {
    __shared__ __align__(16) float2 A[4096];
    __shared__ __align__(16) float2 Bu[4096];
    int bid = blockIdx.x;                 // b*64 + p
    int tid = threadIdx.x;
    int b = bid >> 6, p = bid & 63;
    const float TWO_PI = 6.2831853071795864769f;
    float ang2 = TWO_PI * (float)((tid & 15) * 16) * (1.0f / 4096.0f);
    float ang3 = TWO_PI * (float)tid * (1.0f / 4096.0f);
    float c2 = cosf(ang2), s2 = sinf(ang2);
    float c3 = cosf(ang3), s3 = sinf(ang3);
    float4 acc[4];
#pragma unroll
    for (int t = 0; t < 4; ++t) acc[t] = make_float4(0.f, 0.f, 0.f, 0.f);
    float accny = 0.f;
#pragma unroll
    for (int cc = 0; cc < 4; ++cc) {
        size_t base = (size_t)b * 1048576u + (size_t)(p * 4 + cc);
#pragma unroll
        for (int t = 0; t < 16; ++t) {
            int n = tid + t * 256;
            A[SWZ(n)] = make_float2(q[base + (size_t)n * 256u], k[base + (size_t)n * 256u]);
        }
        __syncthreads();
        fft4096_pp<-1>(A, Bu, c2, -s2, c3, -s3, tid);
        spd_pair_accum(Bu, acc, accny, tid);
        if (cc < 3) __syncthreads();
    }
    float4* dst4 = (float4*)(spd_d + (size_t)bid * SLICE);
#pragma unroll
    for (int t = 0; t < 4; ++t) dst4[tid + t * 256] = acc[t];
    if (tid == 0) spd_d[(size_t)bid * SLICE + 2048] = make_float2(accny, 0.f);
}

// K2: one block per (b,h). Fused d-reduce (8 slices, float4), mirror Hermitian
// spectrum, inverse ping-pong FFT (x 1/N), register top-8, softmax.
__global__ __launch_bounds__(256) void ifft_topk_kernel(const float2* __restrict__ spd_d,
                                                        float* __restrict__ wout,
                                                        int* __restrict__ dout) {
    __shared__ __align__(16) float2 A[4096];
    __shared__ __align__(16) float2 Bu[4096];
    __shared__ float rv[8][4];
    __shared__ int   ri[8][4];
    int bh = blockIdx.x;
    int b = bh >> 3, h = bh & 7;
    int tid = threadIdx.x;
    const float TWO_PI = 6.2831853071795864769f;
    float ang2 = TWO_PI * (float)((tid & 15) * 16) * (1.0f / 4096.0f);
    float ang3 = TWO_PI * (float)tid * (1.0f / 4096.0f);
    float c2 = cosf(ang2), s2 = sinf(ang2);
    float c3 = cosf(ang3), s3 = sinf(ang3);
    const float sc = 1.0f / 4096.0f;
    const float2* base = spd_d + (size_t)(b * 64 + h * 8) * SLICE;
    const float4* base4 = (const float4*)base;
#pragma unroll
    for (int t = 0; t < 4; ++t) {
        int f0 = 2 * tid + 512 * t;
        float4 a = make_float4(0.f, 0.f, 0.f, 0.f);
#pragma unroll
        for (int s = 0; s < 8; ++s) {
            float4 x = base4[(size_t)s * (SLICE / 2) + (size_t)(tid + 256 * t)];
            a.x += x.x; a.y += x.y; a.z += x.z; a.w += x.w;
        }
        float r0 = a.x * sc, i0 = a.y * sc;
        float r1 = a.z * sc, i1 = a.w * sc;
        A[SWZ(f0)]     = make_float2(r0, i0);
        A[SWZ(f0 + 1)] = make_float2(r1, i1);
        if (f0 > 0) A[SWZ(4096 - f0)] = make_float2(r0, -i0);
        A[SWZ(4095 - f0)] = make_float2(r1, -i1);
    }
    if (tid == 0) {
        float ny = 0.f;
#pragma unroll
        for (int s = 0; s < 8; ++s) ny += base[(size_t)s * SLICE + 2048].x;
        A[SWZ(2048)] = make_float2(ny * sc, 0.f);
    }
    __syncthreads();
    fft4096_pp<1>(A, Bu, c2, s2, c3, s3, tid);
    // corr[tau] = Bu[SWZ(tau)].x -> registers
    float cv[16];
#pragma unroll
    for (int t = 0; t < 16; ++t) cv[t] = Bu[SWZ(tid + t * 256)].x;

    int lane = tid & 63, wid = tid >> 6;
    float topv[8]; int topi[8];
    for (int kk = 0; kk < 8; ++kk) {
        float best = -3.0e38f; int bi = 0;
#pragma unroll
        for (int t = 0; t < 16; ++t) {
            int f = tid + t * 256;
            if (cv[t] > best) { best = cv[t]; bi = f; }   // strict > keeps lowest f
        }
#pragma unroll
        for (int off = 32; off > 0; off >>= 1) {
            float ov = __shfl_xor(best, off, 64);
            int   oi = __shfl_xor(bi, off, 64);
            if (ov > best || (ov == best && oi < bi)) { best = ov; bi = oi; }
        }
        if (lane == 0) { rv[kk][wid] = best; ri[kk][wid] = bi; }
        __syncthreads();
        float fb = rv[kk][0]; int fi = ri[kk][0];
#pragma unroll
        for (int w = 1; w < 4; ++w) {
            float ov = rv[kk][w]; int oi = ri[kk][w];
            if (ov > fb || (ov == fb && oi < fi)) { fb = ov; fi = oi; }
        }
        topv[kk] = fb; topi[kk] = fi;
        if (tid == (fi & 255)) {              // owner clears winner (static reg idx)
            int t_owner = fi >> 8;
#pragma unroll
            for (int t = 0; t < 16; ++t)
                if (t == t_owner) cv[t] = -3.0e38f;
        }
    }
    if (tid == 0) {
        float mx = topv[0];
        float e[8], s = 0.0f;
#pragma unroll
        for (int kk = 0; kk < 8; ++kk) { e[kk] = expf(topv[kk] - mx); s += e[kk]; }
        float inv = 1.0f / s;
#pragma unroll
        for (int kk = 0; kk < 8; ++kk) {
            wout[bh * 8 + kk] = e[kk] * inv;
            dout[bh * 8 + kk] = topi[kk];
        }
    }
}

// K3: b-major grid (b = blk & 7 -> per-XCD L2 residency of v[b], 4 MiB).
// One block per 32 l's; thread = (lq, c4), 8 reps; nontemporal out stores.
__global__ __launch_bounds__(256) void agg_kernel(const float4* __restrict__ v4,
                                                  const float* __restrict__ w,
                                                  const int* __restrict__ dl,
                                                  float4* __restrict__ out4) {
    __shared__ float sw[64];
    __shared__ int   sd[64];
    int blk = blockIdx.x;              // lg*8 + b  (b fastest -> XCD round-robin)
    int b = blk & 7, lg = blk >> 3;    // lg in [0,128), 32 l's each
    int tid = threadIdx.x;
    if (tid < 64) {
        int h = tid >> 3, kk = tid & 7;
        sw[tid] = w[(b * 8 + h) * 8 + kk];
        sd[tid] = dl[(b * 8 + h) * 8 + kk];
    }
    __syncthreads();
    int lq = tid >> 6;                 // 0..3
    int c4 = tid & 63;                 // float4 index over 256 floats
    int h  = c4 >> 3;
    float w_[8]; int d_[8];
#pragma unroll
    for (int kk = 0; kk < 8; ++kk) { w_[kk] = sw[h * 8 + kk]; d_[kk] = sd[h * 8 + kk]; }
#pragma unroll
    for (int rep = 0; rep < 8; ++rep) {
        int l = lg * 32 + rep * 4 + lq;
        float4 acc = make_float4(0.f, 0.f, 0.f, 0.f);
#pragma unroll
        for (int kk = 0; kk < 8; ++kk) {
            int l2 = (l + d_[kk]) & 4095;
            float4 x = v4[(size_t)(b * 4096 + l2) * 64u + (size_t)c4];
            acc.x += w_[kk] * x.x; acc.y += w_[kk] * x.y;
            acc.z += w_[kk] * x.z; acc.w += w_[kk] * x.w;
        }
        nfloat4 nv = {acc.x, acc.y, acc.z, acc.w};
        __builtin_nontemporal_store(nv,
            (nfloat4*)&out4[(size_t)(b * 4096 + l) * 64u + (size_t)c4]);
    }
}

extern "C" void kernel_launch(void* const* d_in, const int* in_sizes, int n_in,
                              void* d_out, int out_size, void* d_ws, size_t ws_size,
                              hipStream_t stream) {
    const float* q = (const float*)d_in[0];
    const float* k = (const float*)d_in[1];
    const float* v = (const float*)d_in[2];
    float* ws  = (float*)d_ws;
    // d_out doubles as spd_d scratch: 512 slices x SLICE float2 = 8.4 MB
    // (out is 33.5 MB; agg fully rewrites it last).
    float2* spd_d = (float2*)d_out;

    const size_t XT_FLOATS = 16777216u;     // xT image: 2048 slices x 4096 complex
    const size_t FAST_FLOATS = XT_FLOATS + 1024u;
    bool fast = ws_size >= FAST_FLOATS * sizeof(float);

    if (fast) {
        float* wbuf = ws + XT_FLOATS;       // 512 floats
        int*   dbuf = (int*)(wbuf + 512);   // 512 ints
        transpose_pack_kernel<<<2048, 256, 0, stream>>>((const float4*)q, (const float4*)k,
                                                        (float4*)ws);
        fwd_spd_fast<<<512, 256, 0, stream>>>((const float2*)ws, spd_d);
        ifft_topk_kernel<<<64, 256, 0, stream>>>(spd_d, wbuf, dbuf);
        agg_kernel<<<1024, 256, 0, stream>>>((const float4*)v, wbuf, dbuf, (float4*)d_out);
    } else {
        float* wbuf = ws;
        int*   dbuf = (int*)(wbuf + 512);
        fwd_spd_slow<<<512, 256, 0, stream>>>(q, k, spd_d);
        ifft_topk_kernel<<<64, 256, 0, stream>>>(spd_d, wbuf, dbuf);
        agg_kernel<<<1024, 256, 0, stream>>>((const float4*)v, wbuf, dbuf, (float4*)d_out);
    }
}